// Round 4
// baseline (165.130 us; speedup 1.0000x reference)
//
#include <hip/hip_runtime.h>
#include <math.h>

#define Bn 8
#define Hd 128
#define Ld 8192
#define Pd 256
#define LC 32
#define NC 256  // Ld / LC

typedef __attribute__((ext_vector_type(8))) short bf16x8;
typedef __attribute__((ext_vector_type(4))) float f32x4;
#define MFMA16(a, b, c) __builtin_amdgcn_mfma_f32_16x16x32_bf16(a, b, c, 0, 0, 0)

__device__ __forceinline__ unsigned short f2bf(float f) {
  unsigned u = __float_as_uint(f);
  u = u + 0x7fffu + ((u >> 16) & 1u);
  return (unsigned short)(u >> 16);
}

#if __has_builtin(__builtin_amdgcn_cvt_pk_bf16_f32)
typedef __attribute__((ext_vector_type(2))) __bf16 v2bf_t;
__device__ __forceinline__ unsigned pack2(float a, float b) {
  v2bf_t r = __builtin_amdgcn_cvt_pk_bf16_f32(a, b);  // low = a, high = b
  unsigned u;
  __builtin_memcpy(&u, &r, 4);
  return u;
}
#else
__device__ __forceinline__ unsigned pack2(float a, float b) {
  return (unsigned)f2bf(a) | ((unsigned)f2bf(b) << 16);
}
#endif

__device__ __forceinline__ float bflo(unsigned v) { return __uint_as_float(v << 16); }
__device__ __forceinline__ float bfhi(unsigned v) { return __uint_as_float(v & 0xffff0000u); }

// bu column swizzle: bijective 5-bit perm of p&31 -> <=2-way banks on both the
// acc-layout writes and the per-p row reads.
__device__ __forceinline__ int bperm(int p) {
  return ((p & 4) << 2) | ((p & 16) >> 1) | ((p & 8) >> 1) | (p & 3);
}

// ---------------- kernel 0: repack B,C,D into MFMA A-fragment order ----------------
__global__ void k_prep(const float* __restrict__ Bre, const float* __restrict__ Bim,
                       const float* __restrict__ Cre, const float* __restrict__ Cim,
                       const float* __restrict__ Dm,
                       bf16x8* __restrict__ Bfr, bf16x8* __restrict__ Bfi,
                       bf16x8* __restrict__ Cf, bf16x8* __restrict__ Df) {
  int tid = blockIdx.x * 256 + threadIdx.x;
  int lane = tid & 63, slot = tid >> 6;
  int q = lane >> 4, ln = lane & 15;
  if (slot < 64) {  // B tables
    int ks = slot >> 4, mt = slot & 15;
    int p = mt * 16 + ln;
    bf16x8 vr, vi;
#pragma unroll
    for (int e = 0; e < 8; ++e) {
      int h = ks * 32 + q * 8 + e;
      vr[e] = (short)f2bf(Bre[p * Hd + h]);
      vi[e] = (short)f2bf(Bim[p * Hd + h]);
    }
    Bfr[slot * 64 + lane] = vr;
    Bfi[slot * 64 + lane] = vi;
  } else if (slot < 64 + 128) {  // C table, K' = 512 interleaved (re, -im)
    int s2 = slot - 64;
    int ks = s2 >> 3, mt = s2 & 7;
    int o = mt * 16 + ln;
    bf16x8 v;
#pragma unroll
    for (int e = 0; e < 8; ++e) {
      int kp = ks * 32 + q * 8 + e;
      int p = kp >> 1;
      float val = (kp & 1) ? -Cim[o * Pd + p] : Cre[o * Pd + p];
      v[e] = (short)f2bf(val);
    }
    Cf[s2 * 64 + lane] = v;
  } else if (slot < 64 + 128 + 32) {  // D table
    int s3 = slot - 192;
    int ks = s3 >> 3, mt = s3 & 7;
    int o = mt * 16 + ln;
    bf16x8 v;
#pragma unroll
    for (int e = 0; e < 8; ++e) {
      int h = ks * 32 + q * 8 + e;
      v[e] = (short)f2bf(Dm[o * Hd + h]);
    }
    Df[s3 * 64 + lane] = v;
  }
}

// ---- u staging: 32 rows (j) x 128 bf16 (h), 256 B/row, XOR-swizzled 16B granules
__device__ __forceinline__ void stage_u(const float* __restrict__ ub, unsigned* us32, int t) {
  int lane = t & 63, w = t >> 6;
  int j0 = 4 * (lane & 7);
  int h2 = 16 * w + 2 * (lane >> 3);
  const float* r0 = ub + (size_t)h2 * Ld + j0;
  float4 a0 = *(const float4*)r0;
  float4 a1 = *(const float4*)(r0 + Ld);
  const float* r2 = r0 + (size_t)64 * Ld;
  float4 b0 = *(const float4*)r2;
  float4 b1 = *(const float4*)(r2 + Ld);
  float ta0[4] = {a0.x, a0.y, a0.z, a0.w};
  float ta1[4] = {a1.x, a1.y, a1.z, a1.w};
  float tb0[4] = {b0.x, b0.y, b0.z, b0.w};
  float tb1[4] = {b1.x, b1.y, b1.z, b1.w};
#pragma unroll
  for (int i = 0; i < 4; ++i) {
    int j = j0 + i;
    int g1 = (h2 >> 3) ^ (j & 7);
    us32[(j * 256 + (g1 << 4) + ((2 * h2) & 15)) >> 2] = pack2(ta0[i], ta1[i]);
    int hb = h2 + 64;
    int g2 = (hb >> 3) ^ (j & 7);
    us32[(j * 256 + (g2 << 4) + ((2 * hb) & 15)) >> 2] = pack2(tb0[i], tb1[i]);
  }
}

// ---------------- kernel 1: Bu + du (materialized) + per-chunk E ----------------
__global__ __launch_bounds__(256, 4) void k_chunk(
    const float* __restrict__ u, const float* __restrict__ lre,
    const float* __restrict__ lim, const bf16x8* __restrict__ Bfr,
    const bf16x8* __restrict__ Bfi, const bf16x8* __restrict__ Df,
    float2* __restrict__ E, unsigned* __restrict__ bu_g,
    unsigned* __restrict__ du_g) {
  int bc = blockIdx.x;
  int b = bc >> 8, c = bc & 255;
  __shared__ __align__(16) unsigned char smem[8192 + 32768];  // us 8K + bu 32K
  unsigned* us32 = (unsigned*)smem;
  unsigned* bu32 = (unsigned*)(smem + 8192);
  int t = threadIdx.x;
  int lane = t & 63, w = t >> 6, q = lane >> 4, ln = lane & 15;

  stage_u(u + (size_t)b * Hd * Ld + c * LC, us32, t);
  __syncthreads();

  // ---- Bu (4mt x 2n x {R,I}) and du (2mt x 2n) MFMAs ----
  f32x4 zz = {0.f, 0.f, 0.f, 0.f};
  f32x4 aR[4][2], aI[4][2], dA[2][2];
#pragma unroll
  for (int mt = 0; mt < 4; ++mt)
#pragma unroll
    for (int n = 0; n < 2; ++n) { aR[mt][n] = zz; aI[mt][n] = zz; }
#pragma unroll
  for (int mt = 0; mt < 2; ++mt)
#pragma unroll
    for (int n = 0; n < 2; ++n) dA[mt][n] = zz;

#pragma unroll
  for (int ks = 0; ks < 4; ++ks) {
    bf16x8 ubf[2];
#pragma unroll
    for (int n = 0; n < 2; ++n) {
      int j = 16 * n + ln;
      int g = (4 * ks + q) ^ (j & 7);
      ubf[n] = *(const bf16x8*)((const char*)us32 + j * 256 + g * 16);
    }
#pragma unroll
    for (int mt = 0; mt < 4; ++mt) {
      int tI = ks * 16 + w * 4 + mt;
      bf16x8 ar = Bfr[tI * 64 + lane];
      bf16x8 ai = Bfi[tI * 64 + lane];
#pragma unroll
      for (int n = 0; n < 2; ++n) {
        aR[mt][n] = MFMA16(ar, ubf[n], aR[mt][n]);
        aI[mt][n] = MFMA16(ai, ubf[n], aI[mt][n]);
      }
    }
#pragma unroll
    for (int mt = 0; mt < 2; ++mt) {
      bf16x8 df = Df[(ks * 8 + w * 2 + mt) * 64 + lane];
#pragma unroll
      for (int n = 0; n < 2; ++n) dA[mt][n] = MFMA16(df, ubf[n], dA[mt][n]);
    }
  }

  // du store: pack (n=0, n=1) pairs; du_g[bc*2048 + o*16 + ln]
#pragma unroll
  for (int mt = 0; mt < 2; ++mt)
#pragma unroll
    for (int r = 0; r < 4; ++r) {
      int o = w * 32 + mt * 16 + q * 4 + r;
      du_g[(size_t)bc * 2048 + o * 16 + ln] = pack2(dA[mt][0][r], dA[mt][1][r]);
    }

  // bu -> LDS (swizzled) for the p-major transpose
#pragma unroll
  for (int mt = 0; mt < 4; ++mt)
#pragma unroll
    for (int n = 0; n < 2; ++n)
#pragma unroll
      for (int r = 0; r < 4; ++r) {
        int p = w * 64 + mt * 16 + q * 4 + r;
        int j = 16 * n + ln;
        bu32[(p << 5) | (j ^ bperm(p))] = pack2(aR[mt][n][r], aI[mt][n][r]);
      }
  __syncthreads();

  // ---- thread p: gather row, Horner for E, coalesced bu row store ----
  int p = t;
  int pm = bperm(p);
  unsigned v[LC];
#pragma unroll
  for (int j = 0; j < LC; ++j) v[j] = bu32[(p << 5) | (j ^ pm)];

  float ax = lre[p], ay = lim[p];
  float xr = 0.f, xi = 0.f;
#pragma unroll
  for (int j = 0; j < LC; ++j) {
    float sr = xr + bflo(v[j]), si = xi + bfhi(v[j]);
    xr = ax * sr - ay * si;
    xi = ax * si + ay * sr;
  }
  E[(size_t)bc * Pd + p] = make_float2(xr, xi);

  uint4* dst = (uint4*)(bu_g + ((size_t)bc << 13) + (p << 5));
#pragma unroll
  for (int i = 0; i < 8; ++i)
    dst[i] = make_uint4(v[4 * i], v[4 * i + 1], v[4 * i + 2], v[4 * i + 3]);
}

// ---------------- kernel 2: parallel prefix scan over chunks ----------------
__global__ __launch_bounds__(256) void k_scan(const float* __restrict__ lre,
                                              const float* __restrict__ lim,
                                              float2* __restrict__ E) {
  int g = blockIdx.x * 256 + threadIdx.x;  // 0..16383
  int b = g >> 11;
  int p = (g >> 3) & 255;
  int rq = g & 7;
  float ax = lre[p], ay = lim[p];
  float sx = ax, sy = ay;
#pragma unroll
  for (int k = 0; k < 5; ++k) {  // s = a^32
    float nx = sx * sx - sy * sy, ny = 2.f * sx * sy;
    sx = nx; sy = ny;
  }
  size_t base = ((size_t)(b * NC + rq * 32)) * Pd + p;
  float2 pre[32];
  float cr = 0.f, ci = 0.f;
#pragma unroll 8
  for (int i = 0; i < 32; ++i) {
    float2 e = E[base + (size_t)i * Pd];
    pre[i] = make_float2(cr, ci);
    float nx = sx * cr - sy * ci + e.x;
    float ny = sx * ci + sy * cr + e.y;
    cr = nx; ci = ny;
  }
  float Sx = sx, Sy = sy;
#pragma unroll
  for (int k = 0; k < 5; ++k) {  // S = s^32
    float nx = Sx * Sx - Sy * Sy, ny = 2.f * Sx * Sy;
    Sx = nx; Sy = ny;
  }
  float Vx = cr, Vy = ci;
  float Mx = Sx, My = Sy;
#pragma unroll
  for (int d = 1; d < 8; d <<= 1) {
    float ux = __shfl_up(Vx, d, 8);
    float uy = __shfl_up(Vy, d, 8);
    if (rq >= d) {
      Vx += Mx * ux - My * uy;
      Vy += Mx * uy + My * ux;
    }
    float nx = Mx * Mx - My * My, ny = 2.f * Mx * My;
    Mx = nx; My = ny;
  }
  float Cx = __shfl_up(Vx, 1, 8);
  float Cy = __shfl_up(Vy, 1, 8);
  if (rq == 0) { Cx = 0.f; Cy = 0.f; }
  float tx = 1.f, ty = 0.f;
#pragma unroll 8
  for (int i = 0; i < 32; ++i) {
    float ox = pre[i].x + tx * Cx - ty * Cy;
    float oy = pre[i].y + tx * Cy + ty * Cx;
    E[base + (size_t)i * Pd] = make_float2(ox, oy);
    float nx = tx * sx - ty * sy, ny = tx * sy + ty * sx;
    tx = nx; ty = ny;
  }
}

// ---------------- kernel 3: scan + projection + GELU ----------------
__global__ __launch_bounds__(256, 5) void k_main(
    const float* __restrict__ lre, const float* __restrict__ lim,
    const bf16x8* __restrict__ Cf, const float2* __restrict__ E,
    const unsigned* __restrict__ bu_g, const unsigned* __restrict__ du_g,
    float* __restrict__ out) {
  int bc = blockIdx.x;
  int b = bc >> 8, c = bc & 255;
  __shared__ __align__(16) unsigned xs32[LC * 256];  // 32 KB
  int t = threadIdx.x;
  int lane = t & 63, w = t >> 6, q = lane >> 4, ln = lane & 15;

  // ---- load bu row (contiguous 128 B/thread) + incoming state; scan ----
  int p = t;
  unsigned v[LC];
  const uint4* src = (const uint4*)(bu_g + ((size_t)bc << 13) + (p << 5));
#pragma unroll
  for (int i = 0; i < 8; ++i) {
    uint4 x = src[i];
    v[4 * i] = x.x; v[4 * i + 1] = x.y; v[4 * i + 2] = x.z; v[4 * i + 3] = x.w;
  }
  float2 xin = E[(size_t)bc * Pd + p];
  {
    float ax = lre[p], ay = lim[p];
    float xr = xin.x, xi = xin.y;
#pragma unroll
    for (int j = 0; j < LC; ++j) {
      float sr = xr + bflo(v[j]), si = xi + bfhi(v[j]);
      xr = ax * sr - ay * si;
      xi = ax * si + ay * sr;
      xs32[j * 256 + ((((p >> 2) ^ (j & 7)) << 2) + (p & 3))] = pack2(xr, xi);
    }
  }
  __syncthreads();

  // ---- projection: y = [Cre | -Cim] @ xs_interleaved ----
  f32x4 zz = {0.f, 0.f, 0.f, 0.f};
  f32x4 acc[2][2] = {{zz, zz}, {zz, zz}};
#pragma unroll
  for (int ks = 0; ks < 16; ++ks) {
    bf16x8 xb[2];
#pragma unroll
    for (int n = 0; n < 2; ++n) {
      int j = 16 * n + ln;
      int g = (4 * ks + q) ^ (j & 7);
      xb[n] = *(const bf16x8*)((const char*)xs32 + j * 1024 + g * 16);
    }
#pragma unroll
    for (int mt = 0; mt < 2; ++mt) {
      bf16x8 cf = Cf[(ks * 8 + w * 2 + mt) * 64 + lane];
#pragma unroll
      for (int n = 0; n < 2; ++n) acc[mt][n] = MFMA16(cf, xb[n], acc[mt][n]);
    }
  }

  // ---- + du, GELU (sigmoid form), store ----
#pragma unroll
  for (int mt = 0; mt < 2; ++mt)
#pragma unroll
    for (int r = 0; r < 4; ++r) {
      int o = w * 32 + mt * 16 + q * 4 + r;
      unsigned d32 = du_g[(size_t)bc * 2048 + o * 16 + ln];
      acc[mt][0][r] += bflo(d32);
      acc[mt][1][r] += bfhi(d32);
#pragma unroll
      for (int n = 0; n < 2; ++n) {
        int l = c * LC + 16 * n + ln;
        float vy = acc[mt][n][r];
        float e2 = __builtin_amdgcn_exp2f(-2.4554670f * vy);  // exp(-1.702 v)
        float gy = vy * __builtin_amdgcn_rcpf(1.0f + e2);
        out[((size_t)(b * Hd + o)) * Ld + l] = gy;
      }
    }
}

// ---------------- launch ----------------
extern "C" void kernel_launch(void* const* d_in, const int* in_sizes, int n_in,
                              void* d_out, int out_size, void* d_ws, size_t ws_size,
                              hipStream_t stream) {
  const float* u   = (const float*)d_in[0];
  const float* lre = (const float*)d_in[1];
  const float* lim = (const float*)d_in[2];
  const float* Bre = (const float*)d_in[3];
  const float* Bim = (const float*)d_in[4];
  const float* Cre = (const float*)d_in[5];
  const float* Cim = (const float*)d_in[6];
  const float* Dm  = (const float*)d_in[7];
  float* out = (float*)d_out;

  char* ws = (char*)d_ws;
  bf16x8*  Bfr  = (bf16x8*)(ws);                     // 64 KB
  bf16x8*  Bfi  = (bf16x8*)(ws + 65536);             // 64 KB
  bf16x8*  Cf   = (bf16x8*)(ws + 131072);            // 128 KB
  bf16x8*  Df   = (bf16x8*)(ws + 262144);            // 32 KB
  float2*  E    = (float2*)(ws + (1 << 20));         // 4 MB
  unsigned* bu_g = (unsigned*)(ws + (8ull << 20));   // 64 MB
  unsigned* du_g = (unsigned*)(ws + (80ull << 20));  // 16.8 MB

  k_prep<<<56, 256, 0, stream>>>(Bre, Bim, Cre, Cim, Dm, Bfr, Bfi, Cf, Df);
  k_chunk<<<Bn * NC, 256, 0, stream>>>(u, lre, lim, Bfr, Bfi, Df, E, bu_g, du_g);
  k_scan<<<64, 256, 0, stream>>>(lre, lim, E);
  k_main<<<Bn * NC, 256, 0, stream>>>(lre, lim, Cf, E, bu_g, du_g, out);
}